// Round 9
// baseline (682.132 us; speedup 1.0000x reference)
//
#include <hip/hip_runtime.h>
#include <hip/hip_bf16.h>
#include <cstdint>
#include <cstddef>

typedef __attribute__((ext_vector_type(8))) short bf16x8;
typedef __attribute__((ext_vector_type(4))) short bf16x4;
typedef __attribute__((ext_vector_type(4))) float floatx4;
typedef __attribute__((ext_vector_type(16))) float floatx16;
typedef __attribute__((ext_vector_type(2))) unsigned uintx2;
typedef __attribute__((ext_vector_type(2))) float floatx2;

#define SCALE_L2E 0.20823560929138437f  /* (1/sqrt(48)) * log2(e) */

#define BPH 128          // B*P*H = 8*4*4
#define SEQ 1024
#define DMODEL 192
#define DHEAD 48
#define MROWS 32768      // B*P*N
#define RESCALE_THR 11.5f  /* log2 domain ~ e^8 */
#define VSTRIDE 49152    // elems per bph in v2_ws: 128 ngrp * 48 d * 8

#define ZERO16 {0.f,0.f,0.f,0.f,0.f,0.f,0.f,0.f,0.f,0.f,0.f,0.f,0.f,0.f,0.f,0.f}

__device__ __forceinline__ unsigned short bfu(float f) {
    return __bfloat16_as_ushort(__float2bfloat16(f));
}
__device__ __forceinline__ unsigned pk2(float lo, float hi) {
    return (unsigned)bfu(lo) | ((unsigned)bfu(hi) << 16);
}

// K=8 bf16 MFMA (A,B: 4 bf16 = 2 VGPR; C/D: 16 f32). Prefer the builtin.
#if __has_builtin(__builtin_amdgcn_mfma_f32_32x32x8bf16_1k)
__device__ __forceinline__ floatx16 mfma8(bf16x4 a, bf16x4 b, floatx16 c) {
    return __builtin_amdgcn_mfma_f32_32x32x8bf16_1k(a, b, c, 0, 0, 0);
}
#else
__device__ __forceinline__ floatx16 mfma8(bf16x4 a, bf16x4 b, floatx16 c) {
    asm("v_mfma_f32_32x32x8_bf16 %0, %1, %2, %0" : "+v"(c) : "v"(a), "v"(b));
    return c;
}
#endif

// ---------------------------------------------------------------------------
// Kernel 1: QKV projection (unchanged — proven).
// ---------------------------------------------------------------------------
__global__ __launch_bounds__(256) void qkv_kernel(
    const float* __restrict__ x,
    const float* __restrict__ w_qkv,
    const float* __restrict__ b_qkv,
    unsigned short* __restrict__ q_ws,
    unsigned short* __restrict__ k_ws,
    unsigned short* __restrict__ v2_ws)
{
    __shared__ unsigned short a_lds[64 * 200];
    __shared__ unsigned short w_lds[64 * 200];
    const int t = threadIdx.x;
    const int m0 = blockIdx.x * 64;
    const int n0 = blockIdx.y * 64;

    #pragma unroll
    for (int i = 0; i < 12; ++i) {
        int idx = t + i * 256;
        int row = idx / 48, c4 = idx % 48;
        float4 v = *reinterpret_cast<const float4*>(x + (size_t)(m0 + row) * DMODEL + c4 * 4);
        uintx2 p; p.x = pk2(v.x, v.y); p.y = pk2(v.z, v.w);
        *reinterpret_cast<uintx2*>(&a_lds[row * 200 + c4 * 4]) = p;
    }
    #pragma unroll
    for (int i = 0; i < 12; ++i) {
        int idx = t + i * 256;
        int row = idx / 48, c4 = idx % 48;
        float4 v = *reinterpret_cast<const float4*>(w_qkv + (size_t)(n0 + row) * DMODEL + c4 * 4);
        uintx2 p; p.x = pk2(v.x, v.y); p.y = pk2(v.z, v.w);
        *reinterpret_cast<uintx2*>(&w_lds[row * 200 + c4 * 4]) = p;
    }
    __syncthreads();

    const int lane = t & 63, w = t >> 6;
    const int lrow = lane & 15, lhi = lane >> 4;

    floatx4 zf = {0.f, 0.f, 0.f, 0.f};
    floatx4 acc[4] = {zf, zf, zf, zf};

    #pragma unroll
    for (int ks = 0; ks < 6; ++ks) {
        bf16x8 af = *reinterpret_cast<const bf16x8*>(&a_lds[(w * 16 + lrow) * 200 + ks * 32 + lhi * 8]);
        #pragma unroll
        for (int cb = 0; cb < 4; ++cb) {
            bf16x8 bfr = *reinterpret_cast<const bf16x8*>(&w_lds[(cb * 16 + lrow) * 200 + ks * 32 + lhi * 8]);
            acc[cb] = __builtin_amdgcn_mfma_f32_16x16x32_bf16(af, bfr, acc[cb], 0, 0, 0);
        }
    }

    const int sec = n0 / 192;  // 0=q, 1=k, 2=v (uniform per block)
    if (sec == 2) {
        // V: transpose through LDS -> [ngrp][d][8] stores
        __syncthreads();  // a_lds reads done; reuse as [64 c][72 pad] tile
        #pragma unroll
        for (int cb = 0; cb < 4; ++cb) {
            float bias = b_qkv[n0 + cb * 16 + lrow];
            #pragma unroll
            for (int r = 0; r < 4; ++r)
                a_lds[(cb * 16 + lrow) * 72 + (w * 16 + lhi * 4 + r)] = bfu(acc[cb][r] + bias);
        }
        __syncthreads();
        const int bp = m0 >> 10, nb = m0 & 1023;
        #pragma unroll
        for (int i = 0; i < 2; ++i) {
            int ch = t + i * 256;
            int c_local = ch >> 3, seg = ch & 7;
            int cc = n0 + c_local - 384;
            int h = cc / 48, dd = cc - h * 48;
            *reinterpret_cast<bf16x8*>(
                &v2_ws[(size_t)(bp * 4 + h) * VSTRIDE + (size_t)(nb / 8 + seg) * 384 + dd * 8]) =
                *reinterpret_cast<const bf16x8*>(&a_lds[c_local * 72 + seg * 8]);
        }
    } else {
        #pragma unroll
        for (int cb = 0; cb < 4; ++cb) {
            int c = n0 + cb * 16 + lrow;
            int cc = c - sec * 192;
            int h = cc / 48, dd = cc - h * 48;
            float bias = b_qkv[c];
            #pragma unroll
            for (int r = 0; r < 4; ++r) {
                int m = m0 + w * 16 + lhi * 4 + r;
                float val = acc[cb][r] + bias;
                int bp = m >> 10, n = m & 1023;
                int bph = bp * 4 + h;
                if (sec == 0) {
                    q_ws[((size_t)bph * SEQ + n) * DHEAD + dd] = bfu(val * SCALE_L2E);
                } else {
                    k_ws[((size_t)bph * SEQ + n) * DHEAD + dd] = bfu(val);
                }
            }
        }
    }
}

// ---------------------------------------------------------------------------
// Kernel 2: flash attention with intra-block split-K. 8 waves/block: waves
// 0-3 process kv 0..511, waves 4-7 kv 512..1023, for the same 128 q-rows.
// Doubles resident waves (target 32/CU) to hide the K-load latency that
// capped R3-R8 at ~32% occupancy. Main-loop body identical to R8 (proven
// zero-shuffle K=8 PV). End merge via LDS: half-1 waves dump raw (O,m,l),
// one barrier, half-0 waves combine and write z.
// ---------------------------------------------------------------------------
__global__ __launch_bounds__(512, 7) void attn_kernel(
    const unsigned short* __restrict__ q_ws,
    const unsigned short* __restrict__ k_ws,
    const unsigned short* __restrict__ v2_ws,
    unsigned short* __restrict__ z_ws)
{
    __shared__ float o_lds[4][32][48];     // partner partial O (24 KB)
    __shared__ floatx2 ml_lds[4][32];      // partner (m, l) (1 KB)

    const int t = threadIdx.x, lane = t & 63, w = t >> 6;
    const int q31 = lane & 31, hi = lane >> 5;
    const int hw = w >> 2, wq = w & 3;     // kv-half, q-subtile
    const int d = blockIdx.x;
    const int bph = (d & 7) | ((d >> 6) << 3);
    const int qc = (d >> 3) & 7;
    const int q0 = qc * 128 + wq * 32;
    const int bp = bph >> 2, h = bph & 3;

    // Q fragments (3 k-slices of 16), pre-scaled by SCALE*log2e
    bf16x8 qf[3];
    {
        const unsigned short* qp = q_ws + ((size_t)bph * SEQ + q0 + q31) * DHEAD + hi * 8;
        #pragma unroll
        for (int ks = 0; ks < 3; ++ks)
            qf[ks] = *reinterpret_cast<const bf16x8*>(qp + ks * 16);
    }

    const unsigned short* kp = k_ws + ((size_t)bph * SEQ + q31) * DHEAD + hi * 8;
    const int dB = 32 + (q31 < 16 ? q31 : 15);   // set1 col; lanes 16-31 dup d=47 (unused)
    const unsigned short* vpA = v2_ws + (size_t)bph * VSTRIDE + q31 * 8 + hi * 4;
    const unsigned short* vpB = v2_ws + (size_t)bph * VSTRIDE + dB  * 8 + hi * 4;

    floatx16 oa0 = ZERO16, oa1 = ZERO16;   // d-sets 0-31, 32-47
    float m_prev = -INFINITY, l_sum = 0.f;

    #pragma unroll 1
    for (int kt = 0; kt < 8; ++kt) {
        const int gkt = hw * 8 + kt;       // this half's global tile index
        // ---- all tile loads up front (latency under QK^T + softmax) ----
        const unsigned short* kpt = kp + (size_t)gkt * 64 * DHEAD;
        bf16x8 kf[6];
        #pragma unroll
        for (int ks = 0; ks < 3; ++ks) {
            kf[ks]     = *reinterpret_cast<const bf16x8*>(kpt + ks * 16);
            kf[ks + 3] = *reinterpret_cast<const bf16x8*>(kpt + 32 * DHEAD + ks * 16);
        }
        bf16x4 vA[8], vB[8];
        const size_t vto = (size_t)gkt * 3072;
        #pragma unroll
        for (int j = 0; j < 8; ++j) {
            vA[j] = *reinterpret_cast<const bf16x4*>(vpA + vto + j * 384);
            vB[j] = *reinterpret_cast<const bf16x4*>(vpB + vto + j * 384);
        }

        // ---- S^T = K . Q^T ----
        floatx16 s0 = ZERO16, s1 = ZERO16;
        __builtin_amdgcn_s_setprio(1);
        #pragma unroll
        for (int ks = 0; ks < 3; ++ks) {
            s0 = __builtin_amdgcn_mfma_f32_32x32x16_bf16(kf[ks],     qf[ks], s0, 0, 0, 0);
            s1 = __builtin_amdgcn_mfma_f32_32x32x16_bf16(kf[ks + 3], qf[ks], s1, 0, 0, 0);
        }
        __builtin_amdgcn_s_setprio(0);

        // ---- online softmax (per-lane, q = q31) ----
        float tmax = fmaxf(s0[0], s1[0]);
        #pragma unroll
        for (int r = 1; r < 16; ++r) tmax = fmaxf(tmax, fmaxf(s0[r], s1[r]));
        tmax = fmaxf(tmax, __shfl_xor(tmax, 32, 64));

        if (!__all((int)(tmax <= m_prev + RESCALE_THR))) {
            const float mnew = fmaxf(m_prev, tmax);
            const float scale = exp2f(m_prev - mnew);
            m_prev = mnew;
            l_sum *= scale;
            #pragma unroll
            for (int r = 0; r < 16; ++r) {
                float sr = __shfl(scale, (r & 3) + 8 * (r >> 2) + 4 * hi, 64);
                oa0[r] *= sr;
                oa1[r] *= sr;
            }
        }
        const float mref = m_prev;

        // ---- exp + pack + PV (fully lane-local A-operand) ----
        float ts = 0.f;
        union AU { bf16x4 v; unsigned u[2]; };
        __builtin_amdgcn_s_setprio(1);
        #pragma unroll
        for (int j = 0; j < 8; ++j) {
            float e0, e1, e2, e3;
            if (j < 4) {
                e0 = __builtin_amdgcn_exp2f(s0[4*j]   - mref);
                e1 = __builtin_amdgcn_exp2f(s0[4*j+1] - mref);
                e2 = __builtin_amdgcn_exp2f(s0[4*j+2] - mref);
                e3 = __builtin_amdgcn_exp2f(s0[4*j+3] - mref);
            } else {
                e0 = __builtin_amdgcn_exp2f(s1[4*(j-4)]   - mref);
                e1 = __builtin_amdgcn_exp2f(s1[4*(j-4)+1] - mref);
                e2 = __builtin_amdgcn_exp2f(s1[4*(j-4)+2] - mref);
                e3 = __builtin_amdgcn_exp2f(s1[4*(j-4)+3] - mref);
            }
            ts += (e0 + e1) + (e2 + e3);
            AU aj;
            aj.u[0] = pk2(e0, e1);
            aj.u[1] = pk2(e2, e3);
            oa0 = mfma8(aj.v, vA[j], oa0);
            oa1 = mfma8(aj.v, vB[j], oa1);
        }
        __builtin_amdgcn_s_setprio(0);
        ts += __shfl_xor(ts, 32, 64);
        l_sum += ts;
    }

    // ---- intra-block split-K merge ----
    if (hw == 1) {
        // dump raw partials: O cols d=q31 / 32+q31, rows qr
        #pragma unroll
        for (int r = 0; r < 16; ++r) {
            const int qr = (r & 3) + 8 * (r >> 2) + 4 * hi;
            o_lds[wq][qr][q31] = oa0[r];
            if (q31 < 16) o_lds[wq][qr][32 + q31] = oa1[r];
        }
        if (!hi) { floatx2 ml = {m_prev, l_sum}; ml_lds[wq][q31] = ml; }
    }
    __syncthreads();
    if (hw == 0) {
        const floatx2 ml2 = ml_lds[wq][q31];
        const float mx = fmaxf(m_prev, ml2.x);
        float a1 = exp2f(m_prev - mx), a2 = exp2f(ml2.x - mx);
        const float inv = 1.0f / (l_sum * a1 + ml2.y * a2);
        a1 *= inv; a2 *= inv;
        #pragma unroll
        for (int r = 0; r < 16; ++r) {
            const int qr = (r & 3) + 8 * (r >> 2) + 4 * hi;
            const float f1 = __shfl(a1, qr, 64);
            const float f2 = __shfl(a2, qr, 64);
            unsigned short* zr = z_ws + ((size_t)bp * SEQ + q0 + qr) * DMODEL + h * DHEAD;
            zr[q31] = bfu(oa0[r] * f1 + o_lds[wq][qr][q31] * f2);
            if (q31 < 16)
                zr[32 + q31] = bfu(oa1[r] * f1 + o_lds[wq][qr][32 + q31] * f2);
        }
    }
}

// ---------------------------------------------------------------------------
// Kernel 3: output projection (unchanged — proven).
// ---------------------------------------------------------------------------
__global__ __launch_bounds__(256) void proj_kernel(
    const unsigned short* __restrict__ z_ws,
    const float* __restrict__ w_proj,
    const float* __restrict__ b_proj,
    float* __restrict__ out)
{
    __shared__ unsigned short a_lds[64 * 200];
    __shared__ unsigned short w_lds[64 * 200];
    const int t = threadIdx.x;
    const int m0 = blockIdx.x * 64;
    const int n0 = blockIdx.y * 64;

    for (int i = t; i < 1536; i += 256) {
        int row = i / 24, c8 = i % 24;
        *reinterpret_cast<bf16x8*>(&a_lds[row * 200 + c8 * 8]) =
            *reinterpret_cast<const bf16x8*>(&z_ws[(size_t)(m0 + row) * DMODEL + c8 * 8]);
    }
    #pragma unroll
    for (int i = 0; i < 12; ++i) {
        int idx = t + i * 256;
        int row = idx / 48, c4 = idx % 48;
        float4 v = *reinterpret_cast<const float4*>(w_proj + (size_t)(n0 + row) * DMODEL + c4 * 4);
        uintx2 p; p.x = pk2(v.x, v.y); p.y = pk2(v.z, v.w);
        *reinterpret_cast<uintx2*>(&w_lds[row * 200 + c4 * 4]) = p;
    }
    __syncthreads();

    const int lane = t & 63, w = t >> 6;
    const int lrow = lane & 15, lhi = lane >> 4;

    floatx4 zf = {0.f, 0.f, 0.f, 0.f};
    floatx4 acc[4] = {zf, zf, zf, zf};

    #pragma unroll
    for (int ks = 0; ks < 6; ++ks) {
        bf16x8 af = *reinterpret_cast<const bf16x8*>(&a_lds[(w * 16 + lrow) * 200 + ks * 32 + lhi * 8]);
        #pragma unroll
        for (int cb = 0; cb < 4; ++cb) {
            bf16x8 bfr = *reinterpret_cast<const bf16x8*>(&w_lds[(cb * 16 + lrow) * 200 + ks * 32 + lhi * 8]);
            acc[cb] = __builtin_amdgcn_mfma_f32_16x16x32_bf16(af, bfr, acc[cb], 0, 0, 0);
        }
    }

    #pragma unroll
    for (int cb = 0; cb < 4; ++cb) {
        int c = n0 + cb * 16 + lrow;
        float bias = b_proj[c];
        #pragma unroll
        for (int r = 0; r < 4; ++r) {
            int m = m0 + w * 16 + lhi * 4 + r;
            out[(size_t)m * DMODEL + c] = acc[cb][r] + bias;
        }
    }
}

// ---------------------------------------------------------------------------
extern "C" void kernel_launch(void* const* d_in, const int* in_sizes, int n_in,
                              void* d_out, int out_size, void* d_ws, size_t ws_size,
                              hipStream_t stream) {
    const float* x      = (const float*)d_in[0];
    const float* w_qkv  = (const float*)d_in[1];
    const float* b_qkv  = (const float*)d_in[2];
    const float* w_proj = (const float*)d_in[3];
    const float* b_proj = (const float*)d_in[4];
    float* out = (float*)d_out;

    unsigned short* q_ws  = (unsigned short*)d_ws;
    unsigned short* k_ws  = q_ws  + (size_t)BPH * SEQ * DHEAD;   // 6.29M elems each
    unsigned short* v2_ws = k_ws  + (size_t)BPH * SEQ * DHEAD;
    unsigned short* z_ws  = v2_ws + (size_t)BPH * VSTRIDE;
    // total ws usage: 4 * 12.58 MB = 50.3 MB

    qkv_kernel<<<dim3(512, 9), 256, 0, stream>>>(x, w_qkv, b_qkv, q_ws, k_ws, v2_ws);
    attn_kernel<<<1024, 512, 0, stream>>>(q_ws, k_ws, v2_ws, z_ws);
    proj_kernel<<<dim3(512, 3), 256, 0, stream>>>(z_ws, w_proj, b_proj, out);
}

// Round 10
// 117.447 us; speedup vs baseline: 5.8080x; 5.8080x over previous
//
#include <hip/hip_runtime.h>
#include <hip/hip_bf16.h>
#include <cstdint>
#include <cstddef>

typedef __attribute__((ext_vector_type(8))) short bf16x8;
typedef __attribute__((ext_vector_type(4))) short bf16x4;
typedef __attribute__((ext_vector_type(4))) float floatx4;
typedef __attribute__((ext_vector_type(16))) float floatx16;
typedef __attribute__((ext_vector_type(2))) unsigned uintx2;
typedef __attribute__((ext_vector_type(2))) float floatx2;

#define SCALE_L2E 0.20823560929138437f  /* (1/sqrt(48)) * log2(e) */

#define BPH 128          // B*P*H = 8*4*4
#define SEQ 1024
#define DMODEL 192
#define DHEAD 48
#define MROWS 32768      // B*P*N
#define RESCALE_THR 11.5f  /* log2 domain ~ e^8 */
#define VSTRIDE 49152    // elems per bph in v2_ws: 128 ngrp * 48 d * 8

#define ZERO16 {0.f,0.f,0.f,0.f,0.f,0.f,0.f,0.f,0.f,0.f,0.f,0.f,0.f,0.f,0.f,0.f}

__device__ __forceinline__ unsigned short bfu(float f) {
    return __bfloat16_as_ushort(__float2bfloat16(f));
}
__device__ __forceinline__ unsigned pk2(float lo, float hi) {
    return (unsigned)bfu(lo) | ((unsigned)bfu(hi) << 16);
}

// K=8 bf16 MFMA (A,B: 4 bf16 = 2 VGPR; C/D: 16 f32). Prefer the builtin.
#if __has_builtin(__builtin_amdgcn_mfma_f32_32x32x8bf16_1k)
__device__ __forceinline__ floatx16 mfma8(bf16x4 a, bf16x4 b, floatx16 c) {
    return __builtin_amdgcn_mfma_f32_32x32x8bf16_1k(a, b, c, 0, 0, 0);
}
#else
__device__ __forceinline__ floatx16 mfma8(bf16x4 a, bf16x4 b, floatx16 c) {
    asm("v_mfma_f32_32x32x8_bf16 %0, %1, %2, %0" : "+v"(c) : "v"(a), "v"(b));
    return c;
}
#endif

// ---------------------------------------------------------------------------
// Kernel 1: QKV projection (unchanged — proven).
// ---------------------------------------------------------------------------
__global__ __launch_bounds__(256) void qkv_kernel(
    const float* __restrict__ x,
    const float* __restrict__ w_qkv,
    const float* __restrict__ b_qkv,
    unsigned short* __restrict__ q_ws,
    unsigned short* __restrict__ k_ws,
    unsigned short* __restrict__ v2_ws)
{
    __shared__ unsigned short a_lds[64 * 200];
    __shared__ unsigned short w_lds[64 * 200];
    const int t = threadIdx.x;
    const int m0 = blockIdx.x * 64;
    const int n0 = blockIdx.y * 64;

    #pragma unroll
    for (int i = 0; i < 12; ++i) {
        int idx = t + i * 256;
        int row = idx / 48, c4 = idx % 48;
        float4 v = *reinterpret_cast<const float4*>(x + (size_t)(m0 + row) * DMODEL + c4 * 4);
        uintx2 p; p.x = pk2(v.x, v.y); p.y = pk2(v.z, v.w);
        *reinterpret_cast<uintx2*>(&a_lds[row * 200 + c4 * 4]) = p;
    }
    #pragma unroll
    for (int i = 0; i < 12; ++i) {
        int idx = t + i * 256;
        int row = idx / 48, c4 = idx % 48;
        float4 v = *reinterpret_cast<const float4*>(w_qkv + (size_t)(n0 + row) * DMODEL + c4 * 4);
        uintx2 p; p.x = pk2(v.x, v.y); p.y = pk2(v.z, v.w);
        *reinterpret_cast<uintx2*>(&w_lds[row * 200 + c4 * 4]) = p;
    }
    __syncthreads();

    const int lane = t & 63, w = t >> 6;
    const int lrow = lane & 15, lhi = lane >> 4;

    floatx4 zf = {0.f, 0.f, 0.f, 0.f};
    floatx4 acc[4] = {zf, zf, zf, zf};

    #pragma unroll
    for (int ks = 0; ks < 6; ++ks) {
        bf16x8 af = *reinterpret_cast<const bf16x8*>(&a_lds[(w * 16 + lrow) * 200 + ks * 32 + lhi * 8]);
        #pragma unroll
        for (int cb = 0; cb < 4; ++cb) {
            bf16x8 bfr = *reinterpret_cast<const bf16x8*>(&w_lds[(cb * 16 + lrow) * 200 + ks * 32 + lhi * 8]);
            acc[cb] = __builtin_amdgcn_mfma_f32_16x16x32_bf16(af, bfr, acc[cb], 0, 0, 0);
        }
    }

    const int sec = n0 / 192;  // 0=q, 1=k, 2=v (uniform per block)
    if (sec == 2) {
        // V: transpose through LDS -> [ngrp][d][8] stores
        __syncthreads();  // a_lds reads done; reuse as [64 c][72 pad] tile
        #pragma unroll
        for (int cb = 0; cb < 4; ++cb) {
            float bias = b_qkv[n0 + cb * 16 + lrow];
            #pragma unroll
            for (int r = 0; r < 4; ++r)
                a_lds[(cb * 16 + lrow) * 72 + (w * 16 + lhi * 4 + r)] = bfu(acc[cb][r] + bias);
        }
        __syncthreads();
        const int bp = m0 >> 10, nb = m0 & 1023;
        #pragma unroll
        for (int i = 0; i < 2; ++i) {
            int ch = t + i * 256;
            int c_local = ch >> 3, seg = ch & 7;
            int cc = n0 + c_local - 384;
            int h = cc / 48, dd = cc - h * 48;
            *reinterpret_cast<bf16x8*>(
                &v2_ws[(size_t)(bp * 4 + h) * VSTRIDE + (size_t)(nb / 8 + seg) * 384 + dd * 8]) =
                *reinterpret_cast<const bf16x8*>(&a_lds[c_local * 72 + seg * 8]);
        }
    } else {
        #pragma unroll
        for (int cb = 0; cb < 4; ++cb) {
            int c = n0 + cb * 16 + lrow;
            int cc = c - sec * 192;
            int h = cc / 48, dd = cc - h * 48;
            float bias = b_qkv[c];
            #pragma unroll
            for (int r = 0; r < 4; ++r) {
                int m = m0 + w * 16 + lhi * 4 + r;
                float val = acc[cb][r] + bias;
                int bp = m >> 10, n = m & 1023;
                int bph = bp * 4 + h;
                if (sec == 0) {
                    q_ws[((size_t)bph * SEQ + n) * DHEAD + dd] = bfu(val * SCALE_L2E);
                } else {
                    k_ws[((size_t)bph * SEQ + n) * DHEAD + dd] = bfu(val);
                }
            }
        }
    }
}

// ---------------------------------------------------------------------------
// Kernel 2: flash attention with intra-block split-K. 8 waves/block: waves
// 0-3 process kv 0..511, waves 4-7 kv 512..1023, same 128 q-rows. Doubles
// resident waves to hide K-load latency. launch_bounds(512,4): VGPR cap 128
// (R9's (512,7) capped at ~73 -> catastrophic spill; body needs ~90).
// Main loop = R8's proven zero-shuffle K=8 PV. Merge once at end via LDS.
// ---------------------------------------------------------------------------
__global__ __launch_bounds__(512, 4) void attn_kernel(
    const unsigned short* __restrict__ q_ws,
    const unsigned short* __restrict__ k_ws,
    const unsigned short* __restrict__ v2_ws,
    unsigned short* __restrict__ z_ws)
{
    __shared__ float o_lds[4][32][48];     // partner partial O (24 KB)
    __shared__ floatx2 ml_lds[4][32];      // partner (m, l) (1 KB)

    const int t = threadIdx.x, lane = t & 63, w = t >> 6;
    const int q31 = lane & 31, hi = lane >> 5;
    const int hw = w >> 2, wq = w & 3;     // kv-half, q-subtile
    const int d = blockIdx.x;
    const int bph = (d & 7) | ((d >> 6) << 3);
    const int qc = (d >> 3) & 7;
    const int q0 = qc * 128 + wq * 32;
    const int bp = bph >> 2, h = bph & 3;

    // Q fragments (3 k-slices of 16), pre-scaled by SCALE*log2e
    bf16x8 qf[3];
    {
        const unsigned short* qp = q_ws + ((size_t)bph * SEQ + q0 + q31) * DHEAD + hi * 8;
        #pragma unroll
        for (int ks = 0; ks < 3; ++ks)
            qf[ks] = *reinterpret_cast<const bf16x8*>(qp + ks * 16);
    }

    const unsigned short* kp = k_ws + ((size_t)bph * SEQ + q31) * DHEAD + hi * 8;
    const int dB = 32 + (q31 < 16 ? q31 : 15);   // set1 col; lanes 16-31 dup d=47 (unused)
    const unsigned short* vpA = v2_ws + (size_t)bph * VSTRIDE + q31 * 8 + hi * 4;
    const unsigned short* vpB = v2_ws + (size_t)bph * VSTRIDE + dB  * 8 + hi * 4;

    floatx16 oa0 = ZERO16, oa1 = ZERO16;   // d-sets 0-31, 32-47
    float m_prev = -INFINITY, l_sum = 0.f;

    #pragma unroll 1
    for (int kt = 0; kt < 8; ++kt) {
        const int gkt = hw * 8 + kt;       // this half's global tile index
        // ---- all tile loads up front (latency under QK^T + softmax) ----
        const unsigned short* kpt = kp + (size_t)gkt * 64 * DHEAD;
        bf16x8 kf[6];
        #pragma unroll
        for (int ks = 0; ks < 3; ++ks) {
            kf[ks]     = *reinterpret_cast<const bf16x8*>(kpt + ks * 16);
            kf[ks + 3] = *reinterpret_cast<const bf16x8*>(kpt + 32 * DHEAD + ks * 16);
        }
        bf16x4 vA[8], vB[8];
        const size_t vto = (size_t)gkt * 3072;
        #pragma unroll
        for (int j = 0; j < 8; ++j) {
            vA[j] = *reinterpret_cast<const bf16x4*>(vpA + vto + j * 384);
            vB[j] = *reinterpret_cast<const bf16x4*>(vpB + vto + j * 384);
        }

        // ---- S^T = K . Q^T ----
        floatx16 s0 = ZERO16, s1 = ZERO16;
        __builtin_amdgcn_s_setprio(1);
        #pragma unroll
        for (int ks = 0; ks < 3; ++ks) {
            s0 = __builtin_amdgcn_mfma_f32_32x32x16_bf16(kf[ks],     qf[ks], s0, 0, 0, 0);
            s1 = __builtin_amdgcn_mfma_f32_32x32x16_bf16(kf[ks + 3], qf[ks], s1, 0, 0, 0);
        }
        __builtin_amdgcn_s_setprio(0);

        // ---- online softmax (per-lane, q = q31) ----
        float tmax = fmaxf(s0[0], s1[0]);
        #pragma unroll
        for (int r = 1; r < 16; ++r) tmax = fmaxf(tmax, fmaxf(s0[r], s1[r]));
        tmax = fmaxf(tmax, __shfl_xor(tmax, 32, 64));

        if (!__all((int)(tmax <= m_prev + RESCALE_THR))) {
            const float mnew = fmaxf(m_prev, tmax);
            const float scale = exp2f(m_prev - mnew);
            m_prev = mnew;
            l_sum *= scale;
            #pragma unroll
            for (int r = 0; r < 16; ++r) {
                float sr = __shfl(scale, (r & 3) + 8 * (r >> 2) + 4 * hi, 64);
                oa0[r] *= sr;
                oa1[r] *= sr;
            }
        }
        const float mref = m_prev;

        // ---- exp + pack + PV (fully lane-local A-operand) ----
        float ts = 0.f;
        union AU { bf16x4 v; unsigned u[2]; };
        __builtin_amdgcn_s_setprio(1);
        #pragma unroll
        for (int j = 0; j < 8; ++j) {
            float e0, e1, e2, e3;
            if (j < 4) {
                e0 = __builtin_amdgcn_exp2f(s0[4*j]   - mref);
                e1 = __builtin_amdgcn_exp2f(s0[4*j+1] - mref);
                e2 = __builtin_amdgcn_exp2f(s0[4*j+2] - mref);
                e3 = __builtin_amdgcn_exp2f(s0[4*j+3] - mref);
            } else {
                e0 = __builtin_amdgcn_exp2f(s1[4*(j-4)]   - mref);
                e1 = __builtin_amdgcn_exp2f(s1[4*(j-4)+1] - mref);
                e2 = __builtin_amdgcn_exp2f(s1[4*(j-4)+2] - mref);
                e3 = __builtin_amdgcn_exp2f(s1[4*(j-4)+3] - mref);
            }
            ts += (e0 + e1) + (e2 + e3);
            AU aj;
            aj.u[0] = pk2(e0, e1);
            aj.u[1] = pk2(e2, e3);
            oa0 = mfma8(aj.v, vA[j], oa0);
            oa1 = mfma8(aj.v, vB[j], oa1);
        }
        __builtin_amdgcn_s_setprio(0);
        ts += __shfl_xor(ts, 32, 64);
        l_sum += ts;
    }

    // ---- intra-block split-K merge ----
    if (hw == 1) {
        // dump raw partials: O cols d=q31 / 32+q31, rows qr
        #pragma unroll
        for (int r = 0; r < 16; ++r) {
            const int qr = (r & 3) + 8 * (r >> 2) + 4 * hi;
            o_lds[wq][qr][q31] = oa0[r];
            if (q31 < 16) o_lds[wq][qr][32 + q31] = oa1[r];
        }
        if (!hi) { floatx2 ml = {m_prev, l_sum}; ml_lds[wq][q31] = ml; }
    }
    __syncthreads();
    if (hw == 0) {
        const floatx2 ml2 = ml_lds[wq][q31];
        const float mx = fmaxf(m_prev, ml2.x);
        float a1 = exp2f(m_prev - mx), a2 = exp2f(ml2.x - mx);
        const float inv = 1.0f / (l_sum * a1 + ml2.y * a2);
        a1 *= inv; a2 *= inv;
        #pragma unroll
        for (int r = 0; r < 16; ++r) {
            const int qr = (r & 3) + 8 * (r >> 2) + 4 * hi;
            const float f1 = __shfl(a1, qr, 64);
            const float f2 = __shfl(a2, qr, 64);
            unsigned short* zr = z_ws + ((size_t)bp * SEQ + q0 + qr) * DMODEL + h * DHEAD;
            zr[q31] = bfu(oa0[r] * f1 + o_lds[wq][qr][q31] * f2);
            if (q31 < 16)
                zr[32 + q31] = bfu(oa1[r] * f1 + o_lds[wq][qr][32 + q31] * f2);
        }
    }
}

// ---------------------------------------------------------------------------
// Kernel 3: output projection (unchanged — proven).
// ---------------------------------------------------------------------------
__global__ __launch_bounds__(256) void proj_kernel(
    const unsigned short* __restrict__ z_ws,
    const float* __restrict__ w_proj,
    const float* __restrict__ b_proj,
    float* __restrict__ out)
{
    __shared__ unsigned short a_lds[64 * 200];
    __shared__ unsigned short w_lds[64 * 200];
    const int t = threadIdx.x;
    const int m0 = blockIdx.x * 64;
    const int n0 = blockIdx.y * 64;

    for (int i = t; i < 1536; i += 256) {
        int row = i / 24, c8 = i % 24;
        *reinterpret_cast<bf16x8*>(&a_lds[row * 200 + c8 * 8]) =
            *reinterpret_cast<const bf16x8*>(&z_ws[(size_t)(m0 + row) * DMODEL + c8 * 8]);
    }
    #pragma unroll
    for (int i = 0; i < 12; ++i) {
        int idx = t + i * 256;
        int row = idx / 48, c4 = idx % 48;
        float4 v = *reinterpret_cast<const float4*>(w_proj + (size_t)(n0 + row) * DMODEL + c4 * 4);
        uintx2 p; p.x = pk2(v.x, v.y); p.y = pk2(v.z, v.w);
        *reinterpret_cast<uintx2*>(&w_lds[row * 200 + c4 * 4]) = p;
    }
    __syncthreads();

    const int lane = t & 63, w = t >> 6;
    const int lrow = lane & 15, lhi = lane >> 4;

    floatx4 zf = {0.f, 0.f, 0.f, 0.f};
    floatx4 acc[4] = {zf, zf, zf, zf};

    #pragma unroll
    for (int ks = 0; ks < 6; ++ks) {
        bf16x8 af = *reinterpret_cast<const bf16x8*>(&a_lds[(w * 16 + lrow) * 200 + ks * 32 + lhi * 8]);
        #pragma unroll
        for (int cb = 0; cb < 4; ++cb) {
            bf16x8 bfr = *reinterpret_cast<const bf16x8*>(&w_lds[(cb * 16 + lrow) * 200 + ks * 32 + lhi * 8]);
            acc[cb] = __builtin_amdgcn_mfma_f32_16x16x32_bf16(af, bfr, acc[cb], 0, 0, 0);
        }
    }

    #pragma unroll
    for (int cb = 0; cb < 4; ++cb) {
        int c = n0 + cb * 16 + lrow;
        float bias = b_proj[c];
        #pragma unroll
        for (int r = 0; r < 4; ++r) {
            int m = m0 + w * 16 + lhi * 4 + r;
            out[(size_t)m * DMODEL + c] = acc[cb][r] + bias;
        }
    }
}

// ---------------------------------------------------------------------------
extern "C" void kernel_launch(void* const* d_in, const int* in_sizes, int n_in,
                              void* d_out, int out_size, void* d_ws, size_t ws_size,
                              hipStream_t stream) {
    const float* x      = (const float*)d_in[0];
    const float* w_qkv  = (const float*)d_in[1];
    const float* b_qkv  = (const float*)d_in[2];
    const float* w_proj = (const float*)d_in[3];
    const float* b_proj = (const float*)d_in[4];
    float* out = (float*)d_out;

    unsigned short* q_ws  = (unsigned short*)d_ws;
    unsigned short* k_ws  = q_ws  + (size_t)BPH * SEQ * DHEAD;   // 6.29M elems each
    unsigned short* v2_ws = k_ws  + (size_t)BPH * SEQ * DHEAD;
    unsigned short* z_ws  = v2_ws + (size_t)BPH * VSTRIDE;
    // total ws usage: 4 * 12.58 MB = 50.3 MB

    qkv_kernel<<<dim3(512, 9), 256, 0, stream>>>(x, w_qkv, b_qkv, q_ws, k_ws, v2_ws);
    attn_kernel<<<1024, 512, 0, stream>>>(q_ws, k_ws, v2_ws, z_ws);
    proj_kernel<<<dim3(512, 3), 256, 0, stream>>>(z_ws, w_proj, b_proj, out);
}

// Round 11
// 117.220 us; speedup vs baseline: 5.8192x; 1.0019x over previous
//
#include <hip/hip_runtime.h>
#include <hip/hip_bf16.h>
#include <cstdint>
#include <cstddef>

typedef __attribute__((ext_vector_type(8))) short bf16x8;
typedef __attribute__((ext_vector_type(4))) short bf16x4;
typedef __attribute__((ext_vector_type(4))) float floatx4;
typedef __attribute__((ext_vector_type(16))) float floatx16;
typedef __attribute__((ext_vector_type(2))) unsigned uintx2;
typedef __attribute__((ext_vector_type(2))) float floatx2;

#define SCALE_L2E 0.20823560929138437f  /* (1/sqrt(48)) * log2(e) */

#define BPH 128          // B*P*H = 8*4*4
#define SEQ 1024
#define DMODEL 192
#define DHEAD 48
#define MROWS 32768      // B*P*N
#define RESCALE_THR 11.5f  /* log2 domain ~ e^8 */
#define VSTRIDE 49152    // elems per bph in v2_ws AND k2_ws

#define ZERO16 {0.f,0.f,0.f,0.f,0.f,0.f,0.f,0.f,0.f,0.f,0.f,0.f,0.f,0.f,0.f,0.f}

__device__ __forceinline__ unsigned short bfu(float f) {
    return __bfloat16_as_ushort(__float2bfloat16(f));
}
__device__ __forceinline__ unsigned pk2(float lo, float hi) {
    return (unsigned)bfu(lo) | ((unsigned)bfu(hi) << 16);
}

// K=8 bf16 MFMA (A,B: 4 bf16 = 2 VGPR; C/D: 16 f32). Prefer the builtin.
#if __has_builtin(__builtin_amdgcn_mfma_f32_32x32x8bf16_1k)
__device__ __forceinline__ floatx16 mfma8(bf16x4 a, bf16x4 b, floatx16 c) {
    return __builtin_amdgcn_mfma_f32_32x32x8bf16_1k(a, b, c, 0, 0, 0);
}
#else
__device__ __forceinline__ floatx16 mfma8(bf16x4 a, bf16x4 b, floatx16 c) {
    asm("v_mfma_f32_32x32x8_bf16 %0, %1, %2, %0" : "+v"(c) : "v"(a), "v"(b));
    return c;
}
#endif

// ---------------------------------------------------------------------------
// Kernel 1: QKV projection. q (scaled) -> [bph][n][48].
// K -> k2_ws fragment-ordered: [bph][tile][c=dd>>3][row=n&63][e=dd&7]
//   (tile*3072 + c*512 + row*8 + e) so attn's kf loads are coalesced.
// V -> v2_ws [bph][n>>3][48][8] via LDS transpose (proven).
// ---------------------------------------------------------------------------
__global__ __launch_bounds__(256) void qkv_kernel(
    const float* __restrict__ x,
    const float* __restrict__ w_qkv,
    const float* __restrict__ b_qkv,
    unsigned short* __restrict__ q_ws,
    unsigned short* __restrict__ k2_ws,
    unsigned short* __restrict__ v2_ws)
{
    __shared__ unsigned short a_lds[64 * 200];
    __shared__ unsigned short w_lds[64 * 200];
    const int t = threadIdx.x;
    const int m0 = blockIdx.x * 64;
    const int n0 = blockIdx.y * 64;

    #pragma unroll
    for (int i = 0; i < 12; ++i) {
        int idx = t + i * 256;
        int row = idx / 48, c4 = idx % 48;
        float4 v = *reinterpret_cast<const float4*>(x + (size_t)(m0 + row) * DMODEL + c4 * 4);
        uintx2 p; p.x = pk2(v.x, v.y); p.y = pk2(v.z, v.w);
        *reinterpret_cast<uintx2*>(&a_lds[row * 200 + c4 * 4]) = p;
    }
    #pragma unroll
    for (int i = 0; i < 12; ++i) {
        int idx = t + i * 256;
        int row = idx / 48, c4 = idx % 48;
        float4 v = *reinterpret_cast<const float4*>(w_qkv + (size_t)(n0 + row) * DMODEL + c4 * 4);
        uintx2 p; p.x = pk2(v.x, v.y); p.y = pk2(v.z, v.w);
        *reinterpret_cast<uintx2*>(&w_lds[row * 200 + c4 * 4]) = p;
    }
    __syncthreads();

    const int lane = t & 63, w = t >> 6;
    const int lrow = lane & 15, lhi = lane >> 4;

    floatx4 zf = {0.f, 0.f, 0.f, 0.f};
    floatx4 acc[4] = {zf, zf, zf, zf};

    #pragma unroll
    for (int ks = 0; ks < 6; ++ks) {
        bf16x8 af = *reinterpret_cast<const bf16x8*>(&a_lds[(w * 16 + lrow) * 200 + ks * 32 + lhi * 8]);
        #pragma unroll
        for (int cb = 0; cb < 4; ++cb) {
            bf16x8 bfr = *reinterpret_cast<const bf16x8*>(&w_lds[(cb * 16 + lrow) * 200 + ks * 32 + lhi * 8]);
            acc[cb] = __builtin_amdgcn_mfma_f32_16x16x32_bf16(af, bfr, acc[cb], 0, 0, 0);
        }
    }

    const int sec = n0 / 192;  // 0=q, 1=k, 2=v (uniform per block)
    if (sec == 2) {
        // V: transpose through LDS -> [ngrp][d][8] stores
        __syncthreads();  // a_lds reads done; reuse as [64 c][72 pad] tile
        #pragma unroll
        for (int cb = 0; cb < 4; ++cb) {
            float bias = b_qkv[n0 + cb * 16 + lrow];
            #pragma unroll
            for (int r = 0; r < 4; ++r)
                a_lds[(cb * 16 + lrow) * 72 + (w * 16 + lhi * 4 + r)] = bfu(acc[cb][r] + bias);
        }
        __syncthreads();
        const int bp = m0 >> 10, nb = m0 & 1023;
        #pragma unroll
        for (int i = 0; i < 2; ++i) {
            int ch = t + i * 256;
            int c_local = ch >> 3, seg = ch & 7;
            int cc = n0 + c_local - 384;
            int h = cc / 48, dd = cc - h * 48;
            *reinterpret_cast<bf16x8*>(
                &v2_ws[(size_t)(bp * 4 + h) * VSTRIDE + (size_t)(nb / 8 + seg) * 384 + dd * 8]) =
                *reinterpret_cast<const bf16x8*>(&a_lds[c_local * 72 + seg * 8]);
        }
    } else {
        #pragma unroll
        for (int cb = 0; cb < 4; ++cb) {
            int c = n0 + cb * 16 + lrow;
            int cc = c - sec * 192;
            int h = cc / 48, dd = cc - h * 48;
            float bias = b_qkv[c];
            #pragma unroll
            for (int r = 0; r < 4; ++r) {
                int m = m0 + w * 16 + lhi * 4 + r;
                float val = acc[cb][r] + bias;
                int bp = m >> 10, n = m & 1023;
                int bph = bp * 4 + h;
                if (sec == 0) {
                    q_ws[((size_t)bph * SEQ + n) * DHEAD + dd] = bfu(val * SCALE_L2E);
                } else {
                    // fragment-ordered K2: tile, c-block, row, elem
                    int tile = n >> 6, row = n & 63;
                    int cblk = dd >> 3, e = dd & 7;
                    k2_ws[(size_t)bph * VSTRIDE + tile * 3072 + cblk * 512 + row * 8 + e]
                        = bfu(val);
                }
            }
        }
    }
}

// ---------------------------------------------------------------------------
// Kernel 2: flash attention, split-K (R10 structure, proven) with coalesced
// fragment-ordered K loads: each kf load = two contiguous 512B segments
// (16 cache lines vs 48 for the row-major layout). Everything else identical.
// ---------------------------------------------------------------------------
__global__ __launch_bounds__(512, 4) void attn_kernel(
    const unsigned short* __restrict__ q_ws,
    const unsigned short* __restrict__ k2_ws,
    const unsigned short* __restrict__ v2_ws,
    unsigned short* __restrict__ z_ws)
{
    __shared__ float o_lds[4][32][48];     // partner partial O (24 KB)
    __shared__ floatx2 ml_lds[4][32];      // partner (m, l) (1 KB)

    const int t = threadIdx.x, lane = t & 63, w = t >> 6;
    const int q31 = lane & 31, hi = lane >> 5;
    const int hw = w >> 2, wq = w & 3;     // kv-half, q-subtile
    const int d = blockIdx.x;
    const int bph = (d & 7) | ((d >> 6) << 3);
    const int qc = (d >> 3) & 7;
    const int q0 = qc * 128 + wq * 32;
    const int bp = bph >> 2, h = bph & 3;

    // Q fragments (3 k-slices of 16), pre-scaled by SCALE*log2e
    bf16x8 qf[3];
    {
        const unsigned short* qp = q_ws + ((size_t)bph * SEQ + q0 + q31) * DHEAD + hi * 8;
        #pragma unroll
        for (int ks = 0; ks < 3; ++ks)
            qf[ks] = *reinterpret_cast<const bf16x8*>(qp + ks * 16);
    }

    // K2 per-lane base: lane (q31, hi) reads chunk (c=2ks+hi, row=q31[+32])
    const unsigned short* klane = k2_ws + (size_t)bph * VSTRIDE + hi * 512 + q31 * 8;
    const int dB = 32 + (q31 < 16 ? q31 : 15);   // set1 col; lanes 16-31 dup d=47 (unused)
    const unsigned short* vpA = v2_ws + (size_t)bph * VSTRIDE + q31 * 8 + hi * 4;
    const unsigned short* vpB = v2_ws + (size_t)bph * VSTRIDE + dB  * 8 + hi * 4;

    floatx16 oa0 = ZERO16, oa1 = ZERO16;   // d-sets 0-31, 32-47
    float m_prev = -INFINITY, l_sum = 0.f;

    #pragma unroll 1
    for (int kt = 0; kt < 8; ++kt) {
        const int gkt = hw * 8 + kt;       // this half's global tile index
        // ---- all tile loads up front (latency under QK^T + softmax) ----
        const unsigned short* kpt = klane + (size_t)gkt * 3072;
        bf16x8 kf[6];
        #pragma unroll
        for (int ks = 0; ks < 3; ++ks) {
            kf[ks]     = *reinterpret_cast<const bf16x8*>(kpt + ks * 1024);        // rows 0-31
            kf[ks + 3] = *reinterpret_cast<const bf16x8*>(kpt + ks * 1024 + 256);  // rows 32-63
        }
        bf16x4 vA[8], vB[8];
        const size_t vto = (size_t)gkt * 3072;
        #pragma unroll
        for (int j = 0; j < 8; ++j) {
            vA[j] = *reinterpret_cast<const bf16x4*>(vpA + vto + j * 384);
            vB[j] = *reinterpret_cast<const bf16x4*>(vpB + vto + j * 384);
        }

        // ---- S^T = K . Q^T ----
        floatx16 s0 = ZERO16, s1 = ZERO16;
        __builtin_amdgcn_s_setprio(1);
        #pragma unroll
        for (int ks = 0; ks < 3; ++ks) {
            s0 = __builtin_amdgcn_mfma_f32_32x32x16_bf16(kf[ks],     qf[ks], s0, 0, 0, 0);
            s1 = __builtin_amdgcn_mfma_f32_32x32x16_bf16(kf[ks + 3], qf[ks], s1, 0, 0, 0);
        }
        __builtin_amdgcn_s_setprio(0);

        // ---- online softmax (per-lane, q = q31) ----
        float tmax = fmaxf(s0[0], s1[0]);
        #pragma unroll
        for (int r = 1; r < 16; ++r) tmax = fmaxf(tmax, fmaxf(s0[r], s1[r]));
        tmax = fmaxf(tmax, __shfl_xor(tmax, 32, 64));

        if (!__all((int)(tmax <= m_prev + RESCALE_THR))) {
            const float mnew = fmaxf(m_prev, tmax);
            const float scale = exp2f(m_prev - mnew);
            m_prev = mnew;
            l_sum *= scale;
            #pragma unroll
            for (int r = 0; r < 16; ++r) {
                float sr = __shfl(scale, (r & 3) + 8 * (r >> 2) + 4 * hi, 64);
                oa0[r] *= sr;
                oa1[r] *= sr;
            }
        }
        const float mref = m_prev;

        // ---- exp + pack + PV (fully lane-local A-operand) ----
        float ts = 0.f;
        union AU { bf16x4 v; unsigned u[2]; };
        __builtin_amdgcn_s_setprio(1);
        #pragma unroll
        for (int j = 0; j < 8; ++j) {
            float e0, e1, e2, e3;
            if (j < 4) {
                e0 = __builtin_amdgcn_exp2f(s0[4*j]   - mref);
                e1 = __builtin_amdgcn_exp2f(s0[4*j+1] - mref);
                e2 = __builtin_amdgcn_exp2f(s0[4*j+2] - mref);
                e3 = __builtin_amdgcn_exp2f(s0[4*j+3] - mref);
            } else {
                e0 = __builtin_amdgcn_exp2f(s1[4*(j-4)]   - mref);
                e1 = __builtin_amdgcn_exp2f(s1[4*(j-4)+1] - mref);
                e2 = __builtin_amdgcn_exp2f(s1[4*(j-4)+2] - mref);
                e3 = __builtin_amdgcn_exp2f(s1[4*(j-4)+3] - mref);
            }
            ts += (e0 + e1) + (e2 + e3);
            AU aj;
            aj.u[0] = pk2(e0, e1);
            aj.u[1] = pk2(e2, e3);
            oa0 = mfma8(aj.v, vA[j], oa0);
            oa1 = mfma8(aj.v, vB[j], oa1);
        }
        __builtin_amdgcn_s_setprio(0);
        ts += __shfl_xor(ts, 32, 64);
        l_sum += ts;
    }

    // ---- intra-block split-K merge ----
    if (hw == 1) {
        #pragma unroll
        for (int r = 0; r < 16; ++r) {
            const int qr = (r & 3) + 8 * (r >> 2) + 4 * hi;
            o_lds[wq][qr][q31] = oa0[r];
            if (q31 < 16) o_lds[wq][qr][32 + q31] = oa1[r];
        }
        if (!hi) { floatx2 ml = {m_prev, l_sum}; ml_lds[wq][q31] = ml; }
    }
    __syncthreads();
    if (hw == 0) {
        const floatx2 ml2 = ml_lds[wq][q31];
        const float mx = fmaxf(m_prev, ml2.x);
        float a1 = exp2f(m_prev - mx), a2 = exp2f(ml2.x - mx);
        const float inv = 1.0f / (l_sum * a1 + ml2.y * a2);
        a1 *= inv; a2 *= inv;
        #pragma unroll
        for (int r = 0; r < 16; ++r) {
            const int qr = (r & 3) + 8 * (r >> 2) + 4 * hi;
            const float f1 = __shfl(a1, qr, 64);
            const float f2 = __shfl(a2, qr, 64);
            unsigned short* zr = z_ws + ((size_t)bp * SEQ + q0 + qr) * DMODEL + h * DHEAD;
            zr[q31] = bfu(oa0[r] * f1 + o_lds[wq][qr][q31] * f2);
            if (q31 < 16)
                zr[32 + q31] = bfu(oa1[r] * f1 + o_lds[wq][qr][32 + q31] * f2);
        }
    }
}

// ---------------------------------------------------------------------------
// Kernel 3: output projection (unchanged — proven).
// ---------------------------------------------------------------------------
__global__ __launch_bounds__(256) void proj_kernel(
    const unsigned short* __restrict__ z_ws,
    const float* __restrict__ w_proj,
    const float* __restrict__ b_proj,
    float* __restrict__ out)
{
    __shared__ unsigned short a_lds[64 * 200];
    __shared__ unsigned short w_lds[64 * 200];
    const int t = threadIdx.x;
    const int m0 = blockIdx.x * 64;
    const int n0 = blockIdx.y * 64;

    for (int i = t; i < 1536; i += 256) {
        int row = i / 24, c8 = i % 24;
        *reinterpret_cast<bf16x8*>(&a_lds[row * 200 + c8 * 8]) =
            *reinterpret_cast<const bf16x8*>(&z_ws[(size_t)(m0 + row) * DMODEL + c8 * 8]);
    }
    #pragma unroll
    for (int i = 0; i < 12; ++i) {
        int idx = t + i * 256;
        int row = idx / 48, c4 = idx % 48;
        float4 v = *reinterpret_cast<const float4*>(w_proj + (size_t)(n0 + row) * DMODEL + c4 * 4);
        uintx2 p; p.x = pk2(v.x, v.y); p.y = pk2(v.z, v.w);
        *reinterpret_cast<uintx2*>(&w_lds[row * 200 + c4 * 4]) = p;
    }
    __syncthreads();

    const int lane = t & 63, w = t >> 6;
    const int lrow = lane & 15, lhi = lane >> 4;

    floatx4 zf = {0.f, 0.f, 0.f, 0.f};
    floatx4 acc[4] = {zf, zf, zf, zf};

    #pragma unroll
    for (int ks = 0; ks < 6; ++ks) {
        bf16x8 af = *reinterpret_cast<const bf16x8*>(&a_lds[(w * 16 + lrow) * 200 + ks * 32 + lhi * 8]);
        #pragma unroll
        for (int cb = 0; cb < 4; ++cb) {
            bf16x8 bfr = *reinterpret_cast<const bf16x8*>(&w_lds[(cb * 16 + lrow) * 200 + ks * 32 + lhi * 8]);
            acc[cb] = __builtin_amdgcn_mfma_f32_16x16x32_bf16(af, bfr, acc[cb], 0, 0, 0);
        }
    }

    #pragma unroll
    for (int cb = 0; cb < 4; ++cb) {
        int c = n0 + cb * 16 + lrow;
        float bias = b_proj[c];
        #pragma unroll
        for (int r = 0; r < 4; ++r) {
            int m = m0 + w * 16 + lhi * 4 + r;
            out[(size_t)m * DMODEL + c] = acc[cb][r] + bias;
        }
    }
}

// ---------------------------------------------------------------------------
extern "C" void kernel_launch(void* const* d_in, const int* in_sizes, int n_in,
                              void* d_out, int out_size, void* d_ws, size_t ws_size,
                              hipStream_t stream) {
    const float* x      = (const float*)d_in[0];
    const float* w_qkv  = (const float*)d_in[1];
    const float* b_qkv  = (const float*)d_in[2];
    const float* w_proj = (const float*)d_in[3];
    const float* b_proj = (const float*)d_in[4];
    float* out = (float*)d_out;

    unsigned short* q_ws  = (unsigned short*)d_ws;
    unsigned short* k2_ws = q_ws  + (size_t)BPH * SEQ * DHEAD;   // 6.29M elems each
    unsigned short* v2_ws = k2_ws + (size_t)BPH * VSTRIDE;
    unsigned short* z_ws  = v2_ws + (size_t)BPH * VSTRIDE;
    // total ws usage: 50.3 MB

    qkv_kernel<<<dim3(512, 9), 256, 0, stream>>>(x, w_qkv, b_qkv, q_ws, k2_ws, v2_ws);
    attn_kernel<<<1024, 512, 0, stream>>>(q_ws, k2_ws, v2_ws, z_ws);
    proj_kernel<<<dim3(512, 3), 256, 0, stream>>>(z_ws, w_proj, b_proj, out);
}